// Round 11
// baseline (435.777 us; speedup 1.0000x reference)
//
#include <hip/hip_runtime.h>
#include <hip/hip_bf16.h>

#define D 64

typedef __attribute__((ext_vector_type(8))) short bf16x8;
typedef __attribute__((ext_vector_type(8))) unsigned short u16x8;
typedef __attribute__((ext_vector_type(4))) float f32x4;

__device__ __forceinline__ short f2bf(float x) {
    unsigned u = __float_as_uint(x);
    unsigned r = (u + 0x7fffu + ((u >> 16) & 1u)) >> 16;  // RNE
    return (short)r;
}
__device__ __forceinline__ float bf2f(unsigned short u) {
    return __uint_as_float((unsigned)u << 16);
}

// ---------------- int64-vs-int32 edge_index detection ----------------
__global__ void detect_kernel(const unsigned int* e32, int* flag) {
    __shared__ int nz;
    if (threadIdx.x == 0) nz = 0;
    __syncthreads();
    if (e32[2 * threadIdx.x + 1] != 0) nz = 1;
    __syncthreads();
    if (threadIdx.x == 0) *flag = (nz == 0) ? 1 : 0;
}

__device__ __forceinline__ int load_idx(const void* e, int is64, long long i) {
    if (is64) return (int)((const long long*)e)[i];
    return ((const int*)e)[i];
}

// ================= bucketed CSR build, v3 =================
// Round-8 lesson: per-edge global atomics serialize. Round-10 build still
// histogrammed edges twice and used 65k global reservation atomics. v3:
// materialize per-block histograms; a one-block scan computes exact
// per-(block,bucket) bases; scatter = single edge pass, LDS cursors only,
// ZERO global atomics in the whole build.
#define NBLK 256  // blocks for count & scatter (must match; pbh is per-block)

// ---- B1: per-block LDS bucket histogram -> global pbh[block][512] ----
__global__ __launch_bounds__(256) void bucket_count_kernel(
    const void* edges, const int* flag, int* pbh, int E, int shift) {
    __shared__ int h[512];
    for (int i = threadIdx.x; i < 512; i += 256) h[i] = 0;
    __syncthreads();
    int is64 = *flag;
    int chunk = (E + gridDim.x - 1) / gridDim.x;
    int s0 = blockIdx.x * chunk;
    int s1 = min(E, s0 + chunk);
    for (int e = s0 + (int)threadIdx.x; e < s1; e += 256) {
        int d = load_idx(edges, is64, (long long)E + e);
        atomicAdd(&h[d >> shift], 1);
    }
    __syncthreads();
    for (int i = threadIdx.x; i < 512; i += 256) pbh[blockIdx.x * 512 + i] = h[i];
}

// ---- B2: one block, 512 threads (thread = bucket): column-scan pbh into
// per-(block,bucket) bases (in place) + bucket bases bbase.
__global__ __launch_bounds__(512) void bucket_scan_kernel(
    int* pbh, int* bbase, int nblocks, int E, int nbuk) {
    int b = threadIdx.x;
    int running = 0;
    for (int k = 0; k < nblocks; k++) {
        int idx = k * 512 + b;
        int c = pbh[idx];
        pbh[idx] = running;  // edges of bucket b in blocks < k
        running += c;
    }
    __shared__ int sA[512], sB[512];
    sA[b] = running;  // total[b]
    __syncthreads();
    int* src = sA;
    int* dst = sB;
    for (int d = 1; d < 512; d <<= 1) {
        dst[b] = src[b] + (b >= d ? src[b - d] : 0);
        __syncthreads();
        int* t = src; src = dst; dst = t;
    }
    int excl = src[b] - running;
    bbase[b] = excl;  // for b >= nbuk this equals E (empty buckets)
    if (b == 0) bbase[512] = E;
    __syncthreads();
    for (int k = 0; k < nblocks; k++) pbh[k * 512 + b] += excl;
}

// ---- B3: scatter, single edge pass, LDS cursors preloaded with exact bases ----
__global__ __launch_bounds__(256) void bucket_scatter_kernel(
    const void* edges, const int* flag, const int* pbh, unsigned* staging,
    int E, int shift) {
    __shared__ int cur[512];
    for (int i = threadIdx.x; i < 512; i += 256) cur[i] = pbh[blockIdx.x * 512 + i];
    __syncthreads();
    int is64 = *flag;
    int chunk = (E + gridDim.x - 1) / gridDim.x;
    int s0 = blockIdx.x * chunk;
    int s1 = min(E, s0 + chunk);
    unsigned mask = (unsigned)((1 << shift) - 1);
    for (int e = s0 + (int)threadIdx.x; e < s1; e += 256) {
        int s = load_idx(edges, is64, e);
        int d = load_idx(edges, is64, (long long)E + e);
        int b = d >> shift;
        int pos = atomicAdd(&cur[b], 1);  // LDS atomic
        staging[pos] = ((unsigned)s << shift) | ((unsigned)d & mask);
    }
}

// ---- B4: one block per bucket: LDS counting sort by local dst ->
// coalesced srcs writes + offs + dinv (degree) for the bucket's nodes.
__global__ __launch_bounds__(256) void bucket_fill_kernel(
    const unsigned* __restrict__ staging, const int* __restrict__ bbase,
    int* __restrict__ offs, float* __restrict__ dinv, int* __restrict__ srcs,
    int shift, int n, int E) {
    int b = blockIdx.x;
    int bstart = bbase[b], bend = bbase[b + 1];
    int bsz = 1 << shift;
    unsigned mask = (unsigned)(bsz - 1);
    int v0 = b << shift;
    int nloc = min(bsz, n - v0);

    __shared__ int cnt[512], cur[512], sA[512], sB[512];
    for (int i = threadIdx.x; i < bsz; i += 256) cnt[i] = 0;
    __syncthreads();
    for (int idx = bstart + (int)threadIdx.x; idx < bend; idx += 256)
        atomicAdd(&cnt[staging[idx] & mask], 1);
    __syncthreads();
    for (int i = threadIdx.x; i < bsz; i += 256) sA[i] = cnt[i];
    __syncthreads();
    int* src = sA;
    int* dst = sB;
    for (int d = 1; d < bsz; d <<= 1) {
        for (int i = threadIdx.x; i < bsz; i += 256)
            dst[i] = src[i] + (i >= d ? src[i - d] : 0);
        __syncthreads();
        int* t = src; src = dst; dst = t;
    }
    for (int i = threadIdx.x; i < bsz; i += 256) {
        int excl = src[i] - cnt[i];
        cur[i] = excl;
        if (i < nloc) {
            offs[v0 + i] = bstart + excl;
            dinv[v0 + i] = rsqrtf((float)(cnt[i] + 1));
        }
    }
    if (b == 0 && threadIdx.x == 0) offs[n] = E;
    __syncthreads();
    for (int idx = bstart + (int)threadIdx.x; idx < bend; idx += 256) {
        unsigned u = staging[idx];
        int ld = (int)(u & mask);
        int pos = atomicAdd(&cur[ld], 1);
        srcs[bstart + pos] = (int)(u >> shift);
    }
}

// ---------------- fused (BN+ReLU) -> [n,64]@[64,64] MFMA matmul ----------------
// Input either fp32 (layer 1: x) or bf16 (layers 2-3). BN+ReLU in fp32 on load,
// cvt bf16, 8x mfma_f32_16x16x32_bf16; epilogue scales row r by dinv[r],
// writes bf16 messages T' = dinv[r]*h[r].
__global__ __launch_bounds__(256) void mm_bn_kernel(
    const float* __restrict__ Xf, const unsigned short* __restrict__ Xb, int x_is_bf16,
    const float* __restrict__ W,
    const float* __restrict__ stats, const float* __restrict__ gamma,
    const float* __restrict__ beta, int use_bn, float inv_n,
    const float* __restrict__ dinv,
    unsigned short* __restrict__ Y, int n) {
    int lane = threadIdx.x & 63;
    int m = lane & 15;
    int quad = lane >> 4;

    float sc[16], sh[16];
#pragma unroll
    for (int s = 0; s < 2; s++) {
#pragma unroll
        for (int j = 0; j < 8; j++) {
            float scale = 1.f, shift = 0.f;
            if (use_bn) {
                int f = s * 32 + quad * 8 + j;
                float mean = stats[f] * inv_n;
                float var = stats[64 + f] * inv_n - mean * mean;
                float rs = rsqrtf(var + 1e-5f);
                scale = rs * gamma[f];
                shift = beta[f] - mean * scale;
            }
            sc[s * 8 + j] = scale;
            sh[s * 8 + j] = shift;
        }
    }

    bf16x8 bfrag[4][2];
#pragma unroll
    for (int nt = 0; nt < 4; nt++) {
#pragma unroll
        for (int s = 0; s < 2; s++) {
#pragma unroll
            for (int j = 0; j < 8; j++) {
                int k = s * 32 + quad * 8 + j;
                bfrag[nt][s][j] = f2bf(W[k * 64 + nt * 16 + m]);
            }
        }
    }

    int wave = blockIdx.x * 4 + (threadIdx.x >> 6);
    int nwaves = gridDim.x * 4;
    int ntiles = (n + 15) >> 4;
    const f32x4 zero = {0.f, 0.f, 0.f, 0.f};

    for (int t = wave; t < ntiles; t += nwaves) {
        int r = t * 16 + m;
        if (r >= n) r = n - 1;  // redundant load; stores are guarded
        float av[16];
        if (x_is_bf16) {
            const unsigned short* xr = Xb + (long long)r * 64;
            u16x8 u0 = *(const u16x8*)(xr + quad * 8);
            u16x8 u1 = *(const u16x8*)(xr + 32 + quad * 8);
#pragma unroll
            for (int j = 0; j < 8; j++) {
                av[j] = bf2f(u0[j]);
                av[8 + j] = bf2f(u1[j]);
            }
        } else {
            const float* xr = Xf + (long long)r * 64;
            f32x4 a0 = *(const f32x4*)(xr + quad * 8);
            f32x4 a1 = *(const f32x4*)(xr + quad * 8 + 4);
            f32x4 a2 = *(const f32x4*)(xr + 32 + quad * 8);
            f32x4 a3 = *(const f32x4*)(xr + 32 + quad * 8 + 4);
#pragma unroll
            for (int j = 0; j < 4; j++) {
                av[j] = a0[j];
                av[4 + j] = a1[j];
                av[8 + j] = a2[j];
                av[12 + j] = a3[j];
            }
        }
        bf16x8 A0, A1;
#pragma unroll
        for (int j = 0; j < 8; j++) {
            float v0 = av[j] * sc[j] + sh[j];
            float v1 = av[8 + j] * sc[8 + j] + sh[8 + j];
            if (use_bn) {
                v0 = fmaxf(v0, 0.f);
                v1 = fmaxf(v1, 0.f);
            }
            A0[j] = f2bf(v0);
            A1[j] = f2bf(v1);
        }

        f32x4 acc[4];
#pragma unroll
        for (int nt = 0; nt < 4; nt++) {
            acc[nt] = __builtin_amdgcn_mfma_f32_16x16x32_bf16(A0, bfrag[nt][0], zero, 0, 0, 0);
            acc[nt] = __builtin_amdgcn_mfma_f32_16x16x32_bf16(A1, bfrag[nt][1], acc[nt], 0, 0, 0);
        }

        int row0 = t * 16 + quad * 4;
        float dv[4];
#pragma unroll
        for (int i = 0; i < 4; i++) {
            int rr = row0 + i;
            dv[i] = (rr < n) ? dinv[rr] : 0.f;
        }
#pragma unroll
        for (int nt = 0; nt < 4; nt++) {
#pragma unroll
            for (int i = 0; i < 4; i++) {
                int rr = row0 + i;
                if (rr < n)
                    Y[(long long)rr * 64 + nt * 16 + m] = (unsigned short)f2bf(acc[nt][i] * dv[i]);
            }
        }
    }
}

// ---------------- aggregation: one wave per dst (block churn = MLP) ----------
// Pure gather-sum of pre-scaled bf16 messages; unmasked bulk 8-batches + one
// masked tail batch. Output bf16 (intermediate) or fp32 (final -> d_out).
__global__ __launch_bounds__(256) void agg_kernel(const unsigned short* __restrict__ T,
                                                  const int* __restrict__ offs,
                                                  const int* __restrict__ srcs,
                                                  const float* __restrict__ dinv,
                                                  const float* __restrict__ bias,
                                                  unsigned short* __restrict__ out16,
                                                  float* __restrict__ out32, int out_bf16,
                                                  int n) {
    int v = blockIdx.x * 4 + (threadIdx.x >> 6);
    if (v >= n) return;
    int lane = threadIdx.x & 63;
    float acc = bf2f(T[(long long)v * D + lane]);  // self-loop (pre-scaled)
    int j = offs[v], j1 = offs[v + 1];
    for (; j + 8 <= j1; j += 8) {
        int sidx[8];
#pragma unroll
        for (int u = 0; u < 8; u++) sidx[u] = srcs[j + u];
        float t[8];
#pragma unroll
        for (int u = 0; u < 8; u++) t[u] = bf2f(T[(long long)sidx[u] * D + lane]);
        acc += ((t[0] + t[1]) + (t[2] + t[3])) + ((t[4] + t[5]) + (t[6] + t[7]));
    }
    if (j < j1) {  // single masked tail batch
        int sidx[8];
        float wgt[8];
#pragma unroll
        for (int u = 0; u < 8; u++) {
            int jj = j + u;
            int jc = jj < j1 ? jj : j1 - 1;
            sidx[u] = srcs[jc];
            wgt[u] = (jj < j1) ? 1.f : 0.f;
        }
        float t[8];
#pragma unroll
        for (int u = 0; u < 8; u++) t[u] = bf2f(T[(long long)sidx[u] * D + lane]);
        float p0 = wgt[0] * t[0] + wgt[1] * t[1];
        float p1 = wgt[2] * t[2] + wgt[3] * t[3];
        float p2 = wgt[4] * t[4] + wgt[5] * t[5];
        float p3 = wgt[6] * t[6] + wgt[7] * t[7];
        acc += (p0 + p1) + (p2 + p3);
    }
    float val = dinv[v] * acc + bias[lane];
    if (out_bf16)
        out16[(long long)v * D + lane] = (unsigned short)f2bf(val);
    else
        out32[(long long)v * D + lane] = val;
}

// ---------------- batchnorm stats (bf16 input) ----------------
__global__ __launch_bounds__(256) void bnstats_kernel(const unsigned short* __restrict__ H,
                                                      float* __restrict__ stats, int n) {
    int f = threadIdx.x & 63;
    int r = threadIdx.x >> 6;
    float s = 0.f, q = 0.f;
    for (int node = blockIdx.x * 4 + r; node < n; node += gridDim.x * 4) {
        float x = bf2f(H[(long long)node * D + f]);
        s += x;
        q += x * x;
    }
    __shared__ float ls[256], lq[256];
    ls[threadIdx.x] = s;
    lq[threadIdx.x] = q;
    __syncthreads();
    if (r == 0) {
        s = ls[f] + ls[64 + f] + ls[128 + f] + ls[192 + f];
        q = lq[f] + lq[64 + f] + lq[128 + f] + lq[192 + f];
        atomicAdd(&stats[f], s);
        atomicAdd(&stats[64 + f], q);
    }
}

// ---------------- host ----------------
extern "C" void kernel_launch(void* const* d_in, const int* in_sizes, int n_in,
                              void* d_out, int out_size, void* d_ws, size_t ws_size,
                              hipStream_t stream) {
    const float* x = (const float*)d_in[0];
    const void* edges = d_in[1];
    const float* W1 = (const float*)d_in[3];
    const float* b1 = (const float*)d_in[4];
    const float* gamma1 = (const float*)d_in[5];
    const float* beta1 = (const float*)d_in[6];
    const float* W2 = (const float*)d_in[7];
    const float* b2 = (const float*)d_in[8];
    const float* gamma2 = (const float*)d_in[9];
    const float* beta2 = (const float*)d_in[10];
    const float* W3 = (const float*)d_in[11];
    const float* b3 = (const float*)d_in[12];

    const int N = in_sizes[0] / D;
    const int E = in_sizes[1] / 2;
    const float inv_n = 1.f / (float)N;

    int shift = 8;
    while ((((long long)N - 1) >> shift) + 1 > 512) shift++;
    const int nbuk = (int)(((long long)N - 1) >> shift) + 1;

    char* ws = (char*)d_ws;
    size_t off = 0;
    auto alloc = [&](size_t bytes) -> void* {
        void* p = ws + off;
        off = (off + bytes + 255) & ~(size_t)255;
        return p;
    };
    float*    dinv    = (float*)   alloc((size_t)N * 4);
    int*      offs    = (int*)     alloc((size_t)(N + 1) * 4);
    int*      srcs    = (int*)     alloc((size_t)E * 4);
    unsigned* staging = (unsigned*)alloc((size_t)E * 4);
    int*      pbh     = (int*)     alloc((size_t)NBLK * 512 * 4);
    int*      bbase   = (int*)     alloc(513 * 4);
    int*      flag    = (int*)     alloc(4);
    float*    stats   = (float*)   alloc(256 * 4);  // [0:128)=layer1, [128:256)=layer2
    unsigned short* bufA = (unsigned short*)alloc((size_t)N * D * 2);  // bf16 messages
    unsigned short* hbuf = (unsigned short*)alloc((size_t)N * D * 2);  // bf16 node feats
    float*    outf    = (float*)d_out;  // final fp32 output

    const int aggb = (N + 3) / 4;

    // ---- bucketed CSR build v3 (once, reused 3x; zero global atomics) ----
    detect_kernel<<<1, 256, 0, stream>>>((const unsigned int*)edges, flag);
    bucket_count_kernel<<<NBLK, 256, 0, stream>>>(edges, flag, pbh, E, shift);
    bucket_scan_kernel<<<1, 512, 0, stream>>>(pbh, bbase, NBLK, E, nbuk);
    bucket_scatter_kernel<<<NBLK, 256, 0, stream>>>(edges, flag, pbh, staging, E, shift);
    bucket_fill_kernel<<<nbuk, 256, 0, stream>>>(staging, bbase, offs, dinv, srcs, shift, N, E);
    hipMemsetAsync(stats, 0, 256 * 4, stream);  // both layers' stats in one memset

    // ---- layer 1 (x fp32 in; hbuf bf16 out) ----
    mm_bn_kernel<<<512, 256, 0, stream>>>(x, nullptr, 0, W1, nullptr, nullptr, nullptr, 0,
                                          inv_n, dinv, bufA, N);
    agg_kernel<<<aggb, 256, 0, stream>>>(bufA, offs, srcs, dinv, b1, hbuf, nullptr, 1, N);
    bnstats_kernel<<<512, 256, 0, stream>>>(hbuf, stats, N);

    // ---- layer 2 (hbuf bf16 in; BN1+ReLU fused; hbuf bf16 out) ----
    mm_bn_kernel<<<512, 256, 0, stream>>>(nullptr, hbuf, 1, W2, stats, gamma1, beta1, 1,
                                          inv_n, dinv, bufA, N);
    agg_kernel<<<aggb, 256, 0, stream>>>(bufA, offs, srcs, dinv, b2, hbuf, nullptr, 1, N);
    bnstats_kernel<<<512, 256, 0, stream>>>(hbuf, stats + 128, N);

    // ---- layer 3 (hbuf bf16 in; BN2+ReLU fused; fp32 out to d_out) ----
    mm_bn_kernel<<<512, 256, 0, stream>>>(nullptr, hbuf, 1, W3, stats + 128, gamma2, beta2, 1,
                                          inv_n, dinv, bufA, N);
    agg_kernel<<<aggb, 256, 0, stream>>>(bufA, offs, srcs, dinv, b3, nullptr, outf, 0, N);
}

// Round 12
// 365.513 us; speedup vs baseline: 1.1922x; 1.1922x over previous
//
#include <hip/hip_runtime.h>
#include <hip/hip_bf16.h>

#define D 64

typedef __attribute__((ext_vector_type(8))) short bf16x8;
typedef __attribute__((ext_vector_type(8))) unsigned short u16x8;
typedef __attribute__((ext_vector_type(4))) float f32x4;

__device__ __forceinline__ short f2bf(float x) {
    unsigned u = __float_as_uint(x);
    unsigned r = (u + 0x7fffu + ((u >> 16) & 1u)) >> 16;  // RNE
    return (short)r;
}
__device__ __forceinline__ float bf2f(unsigned short u) {
    return __uint_as_float((unsigned)u << 16);
}

// ---------------- int64-vs-int32 edge_index detection ----------------
__global__ void detect_kernel(const unsigned int* e32, int* flag) {
    __shared__ int nz;
    if (threadIdx.x == 0) nz = 0;
    __syncthreads();
    if (e32[2 * threadIdx.x + 1] != 0) nz = 1;
    __syncthreads();
    if (threadIdx.x == 0) *flag = (nz == 0) ? 1 : 0;
}

__device__ __forceinline__ int load_idx(const void* e, int is64, long long i) {
    if (is64) return (int)((const long long*)e)[i];
    return ((const int*)e)[i];
}

// ================= bucketed CSR build, v4 =================
// v3 lesson: the one-block column scan serialized 256 strided loads -> 83us.
// v4 parallelizes it: colscan (512 blocks, bucket each) + basescan (1 block).
// Still zero global atomics; scatter folds bbase into its LDS cursors.
#define NBLK 256  // blocks for count & scatter (pbh rows)

// ---- B1: per-block LDS bucket histogram -> global pbh[block][512] ----
__global__ __launch_bounds__(256) void bucket_count_kernel(
    const void* edges, const int* flag, int* pbh, int E, int shift) {
    __shared__ int h[512];
    for (int i = threadIdx.x; i < 512; i += 256) h[i] = 0;
    __syncthreads();
    int is64 = *flag;
    int chunk = (E + gridDim.x - 1) / gridDim.x;
    int s0 = blockIdx.x * chunk;
    int s1 = min(E, s0 + chunk);
    for (int e = s0 + (int)threadIdx.x; e < s1; e += 256) {
        int d = load_idx(edges, is64, (long long)E + e);
        atomicAdd(&h[d >> shift], 1);
    }
    __syncthreads();
    for (int i = threadIdx.x; i < 512; i += 256) pbh[blockIdx.x * 512 + i] = h[i];
}

// ---- B2a: per-bucket column scan (block = bucket, thread = count-block) ----
// pbh[k][b] <- sum of pbh[<k][b] (exclusive); btot[b] <- column total.
__global__ __launch_bounds__(256) void colscan_kernel(int* pbh, int* btot) {
    int b = blockIdx.x;  // bucket
    int k = threadIdx.x; // count-block
    __shared__ int sA[256], sB[256];
    int v = pbh[k * 512 + b];
    sA[k] = v;
    __syncthreads();
    int* src = sA;
    int* dst = sB;
    for (int d = 1; d < 256; d <<= 1) {
        dst[k] = src[k] + (k >= d ? src[k - d] : 0);
        __syncthreads();
        int* t = src; src = dst; dst = t;
    }
    pbh[k * 512 + b] = src[k] - v;  // exclusive prefix within column
    if (k == 255) btot[b] = src[255];
}

// ---- B2b: single-block scan of 512 bucket totals -> bbase ----
__global__ __launch_bounds__(512) void basescan_kernel(const int* btot, int* bbase, int E) {
    __shared__ int sA[512], sB[512];
    int b = threadIdx.x;
    int v = btot[b];
    sA[b] = v;
    __syncthreads();
    int* src = sA;
    int* dst = sB;
    for (int d = 1; d < 512; d <<= 1) {
        dst[b] = src[b] + (b >= d ? src[b - d] : 0);
        __syncthreads();
        int* t = src; src = dst; dst = t;
    }
    bbase[b] = src[b] - v;
    if (b == 0) bbase[512] = E;
}

// ---- B3: scatter, single edge pass, LDS cursors = pbh prefix + bbase ----
__global__ __launch_bounds__(256) void bucket_scatter_kernel(
    const void* edges, const int* flag, const int* pbh, const int* bbase,
    unsigned* staging, int E, int shift) {
    __shared__ int cur[512];
    for (int i = threadIdx.x; i < 512; i += 256)
        cur[i] = pbh[blockIdx.x * 512 + i] + bbase[i];
    __syncthreads();
    int is64 = *flag;
    int chunk = (E + gridDim.x - 1) / gridDim.x;
    int s0 = blockIdx.x * chunk;
    int s1 = min(E, s0 + chunk);
    unsigned mask = (unsigned)((1 << shift) - 1);
    for (int e = s0 + (int)threadIdx.x; e < s1; e += 256) {
        int s = load_idx(edges, is64, e);
        int d = load_idx(edges, is64, (long long)E + e);
        int b = d >> shift;
        int pos = atomicAdd(&cur[b], 1);  // LDS atomic
        staging[pos] = ((unsigned)s << shift) | ((unsigned)d & mask);
    }
}

// ---- B4: one block per bucket: LDS counting sort by local dst ->
// coalesced srcs writes + offs + dinv (degree) for the bucket's nodes.
__global__ __launch_bounds__(256) void bucket_fill_kernel(
    const unsigned* __restrict__ staging, const int* __restrict__ bbase,
    int* __restrict__ offs, float* __restrict__ dinv, int* __restrict__ srcs,
    int shift, int n, int E) {
    int b = blockIdx.x;
    int bstart = bbase[b], bend = bbase[b + 1];
    int bsz = 1 << shift;
    unsigned mask = (unsigned)(bsz - 1);
    int v0 = b << shift;
    int nloc = min(bsz, n - v0);

    __shared__ int cnt[512], cur[512], sA[512], sB[512];
    for (int i = threadIdx.x; i < bsz; i += 256) cnt[i] = 0;
    __syncthreads();
    for (int idx = bstart + (int)threadIdx.x; idx < bend; idx += 256)
        atomicAdd(&cnt[staging[idx] & mask], 1);
    __syncthreads();
    for (int i = threadIdx.x; i < bsz; i += 256) sA[i] = cnt[i];
    __syncthreads();
    int* src = sA;
    int* dst = sB;
    for (int d = 1; d < bsz; d <<= 1) {
        for (int i = threadIdx.x; i < bsz; i += 256)
            dst[i] = src[i] + (i >= d ? src[i - d] : 0);
        __syncthreads();
        int* t = src; src = dst; dst = t;
    }
    for (int i = threadIdx.x; i < bsz; i += 256) {
        int excl = src[i] - cnt[i];
        cur[i] = excl;
        if (i < nloc) {
            offs[v0 + i] = bstart + excl;
            dinv[v0 + i] = rsqrtf((float)(cnt[i] + 1));
        }
    }
    if (b == 0 && threadIdx.x == 0) offs[n] = E;
    __syncthreads();
    for (int idx = bstart + (int)threadIdx.x; idx < bend; idx += 256) {
        unsigned u = staging[idx];
        int ld = (int)(u & mask);
        int pos = atomicAdd(&cur[ld], 1);
        srcs[bstart + pos] = (int)(u >> shift);
    }
}

// ---------------- fused (BN+ReLU) -> [n,64]@[64,64] MFMA matmul ----------------
__global__ __launch_bounds__(256) void mm_bn_kernel(
    const float* __restrict__ Xf, const unsigned short* __restrict__ Xb, int x_is_bf16,
    const float* __restrict__ W,
    const float* __restrict__ stats, const float* __restrict__ gamma,
    const float* __restrict__ beta, int use_bn, float inv_n,
    const float* __restrict__ dinv,
    unsigned short* __restrict__ Y, int n) {
    int lane = threadIdx.x & 63;
    int m = lane & 15;
    int quad = lane >> 4;

    float sc[16], sh[16];
#pragma unroll
    for (int s = 0; s < 2; s++) {
#pragma unroll
        for (int j = 0; j < 8; j++) {
            float scale = 1.f, shift = 0.f;
            if (use_bn) {
                int f = s * 32 + quad * 8 + j;
                float mean = stats[f] * inv_n;
                float var = stats[64 + f] * inv_n - mean * mean;
                float rs = rsqrtf(var + 1e-5f);
                scale = rs * gamma[f];
                shift = beta[f] - mean * scale;
            }
            sc[s * 8 + j] = scale;
            sh[s * 8 + j] = shift;
        }
    }

    bf16x8 bfrag[4][2];
#pragma unroll
    for (int nt = 0; nt < 4; nt++) {
#pragma unroll
        for (int s = 0; s < 2; s++) {
#pragma unroll
            for (int j = 0; j < 8; j++) {
                int k = s * 32 + quad * 8 + j;
                bfrag[nt][s][j] = f2bf(W[k * 64 + nt * 16 + m]);
            }
        }
    }

    int wave = blockIdx.x * 4 + (threadIdx.x >> 6);
    int nwaves = gridDim.x * 4;
    int ntiles = (n + 15) >> 4;
    const f32x4 zero = {0.f, 0.f, 0.f, 0.f};

    for (int t = wave; t < ntiles; t += nwaves) {
        int r = t * 16 + m;
        if (r >= n) r = n - 1;  // redundant load; stores are guarded
        float av[16];
        if (x_is_bf16) {
            const unsigned short* xr = Xb + (long long)r * 64;
            u16x8 u0 = *(const u16x8*)(xr + quad * 8);
            u16x8 u1 = *(const u16x8*)(xr + 32 + quad * 8);
#pragma unroll
            for (int j = 0; j < 8; j++) {
                av[j] = bf2f(u0[j]);
                av[8 + j] = bf2f(u1[j]);
            }
        } else {
            const float* xr = Xf + (long long)r * 64;
            f32x4 a0 = *(const f32x4*)(xr + quad * 8);
            f32x4 a1 = *(const f32x4*)(xr + quad * 8 + 4);
            f32x4 a2 = *(const f32x4*)(xr + 32 + quad * 8);
            f32x4 a3 = *(const f32x4*)(xr + 32 + quad * 8 + 4);
#pragma unroll
            for (int j = 0; j < 4; j++) {
                av[j] = a0[j];
                av[4 + j] = a1[j];
                av[8 + j] = a2[j];
                av[12 + j] = a3[j];
            }
        }
        bf16x8 A0, A1;
#pragma unroll
        for (int j = 0; j < 8; j++) {
            float v0 = av[j] * sc[j] + sh[j];
            float v1 = av[8 + j] * sc[8 + j] + sh[8 + j];
            if (use_bn) {
                v0 = fmaxf(v0, 0.f);
                v1 = fmaxf(v1, 0.f);
            }
            A0[j] = f2bf(v0);
            A1[j] = f2bf(v1);
        }

        f32x4 acc[4];
#pragma unroll
        for (int nt = 0; nt < 4; nt++) {
            acc[nt] = __builtin_amdgcn_mfma_f32_16x16x32_bf16(A0, bfrag[nt][0], zero, 0, 0, 0);
            acc[nt] = __builtin_amdgcn_mfma_f32_16x16x32_bf16(A1, bfrag[nt][1], acc[nt], 0, 0, 0);
        }

        int row0 = t * 16 + quad * 4;
        float dv[4];
#pragma unroll
        for (int i = 0; i < 4; i++) {
            int rr = row0 + i;
            dv[i] = (rr < n) ? dinv[rr] : 0.f;
        }
#pragma unroll
        for (int nt = 0; nt < 4; nt++) {
#pragma unroll
            for (int i = 0; i < 4; i++) {
                int rr = row0 + i;
                if (rr < n)
                    Y[(long long)rr * 64 + nt * 16 + m] = (unsigned short)f2bf(acc[nt][i] * dv[i]);
            }
        }
    }
}

// ---------------- aggregation: one wave per dst (block churn = MLP) ----------
__global__ __launch_bounds__(256) void agg_kernel(const unsigned short* __restrict__ T,
                                                  const int* __restrict__ offs,
                                                  const int* __restrict__ srcs,
                                                  const float* __restrict__ dinv,
                                                  const float* __restrict__ bias,
                                                  unsigned short* __restrict__ out16,
                                                  float* __restrict__ out32, int out_bf16,
                                                  int n) {
    int v = blockIdx.x * 4 + (threadIdx.x >> 6);
    if (v >= n) return;
    int lane = threadIdx.x & 63;
    float acc = bf2f(T[(long long)v * D + lane]);  // self-loop (pre-scaled)
    int j = offs[v], j1 = offs[v + 1];
    for (; j + 8 <= j1; j += 8) {
        int sidx[8];
#pragma unroll
        for (int u = 0; u < 8; u++) sidx[u] = srcs[j + u];
        float t[8];
#pragma unroll
        for (int u = 0; u < 8; u++) t[u] = bf2f(T[(long long)sidx[u] * D + lane]);
        acc += ((t[0] + t[1]) + (t[2] + t[3])) + ((t[4] + t[5]) + (t[6] + t[7]));
    }
    if (j < j1) {  // single masked tail batch
        int sidx[8];
        float wgt[8];
#pragma unroll
        for (int u = 0; u < 8; u++) {
            int jj = j + u;
            int jc = jj < j1 ? jj : j1 - 1;
            sidx[u] = srcs[jc];
            wgt[u] = (jj < j1) ? 1.f : 0.f;
        }
        float t[8];
#pragma unroll
        for (int u = 0; u < 8; u++) t[u] = bf2f(T[(long long)sidx[u] * D + lane]);
        float p0 = wgt[0] * t[0] + wgt[1] * t[1];
        float p1 = wgt[2] * t[2] + wgt[3] * t[3];
        float p2 = wgt[4] * t[4] + wgt[5] * t[5];
        float p3 = wgt[6] * t[6] + wgt[7] * t[7];
        acc += (p0 + p1) + (p2 + p3);
    }
    float val = dinv[v] * acc + bias[lane];
    if (out_bf16)
        out16[(long long)v * D + lane] = (unsigned short)f2bf(val);
    else
        out32[(long long)v * D + lane] = val;
}

// ---------------- batchnorm stats (bf16 input) ----------------
__global__ __launch_bounds__(256) void bnstats_kernel(const unsigned short* __restrict__ H,
                                                      float* __restrict__ stats, int n) {
    int f = threadIdx.x & 63;
    int r = threadIdx.x >> 6;
    float s = 0.f, q = 0.f;
    for (int node = blockIdx.x * 4 + r; node < n; node += gridDim.x * 4) {
        float x = bf2f(H[(long long)node * D + f]);
        s += x;
        q += x * x;
    }
    __shared__ float ls[256], lq[256];
    ls[threadIdx.x] = s;
    lq[threadIdx.x] = q;
    __syncthreads();
    if (r == 0) {
        s = ls[f] + ls[64 + f] + ls[128 + f] + ls[192 + f];
        q = lq[f] + lq[64 + f] + lq[128 + f] + lq[192 + f];
        atomicAdd(&stats[f], s);
        atomicAdd(&stats[64 + f], q);
    }
}

// ---------------- host ----------------
extern "C" void kernel_launch(void* const* d_in, const int* in_sizes, int n_in,
                              void* d_out, int out_size, void* d_ws, size_t ws_size,
                              hipStream_t stream) {
    const float* x = (const float*)d_in[0];
    const void* edges = d_in[1];
    const float* W1 = (const float*)d_in[3];
    const float* b1 = (const float*)d_in[4];
    const float* gamma1 = (const float*)d_in[5];
    const float* beta1 = (const float*)d_in[6];
    const float* W2 = (const float*)d_in[7];
    const float* b2 = (const float*)d_in[8];
    const float* gamma2 = (const float*)d_in[9];
    const float* beta2 = (const float*)d_in[10];
    const float* W3 = (const float*)d_in[11];
    const float* b3 = (const float*)d_in[12];

    const int N = in_sizes[0] / D;
    const int E = in_sizes[1] / 2;
    const float inv_n = 1.f / (float)N;

    int shift = 8;
    while ((((long long)N - 1) >> shift) + 1 > 512) shift++;
    const int nbuk = (int)(((long long)N - 1) >> shift) + 1;

    char* ws = (char*)d_ws;
    size_t off = 0;
    auto alloc = [&](size_t bytes) -> void* {
        void* p = ws + off;
        off = (off + bytes + 255) & ~(size_t)255;
        return p;
    };
    float*    dinv    = (float*)   alloc((size_t)N * 4);
    int*      offs    = (int*)     alloc((size_t)(N + 1) * 4);
    int*      srcs    = (int*)     alloc((size_t)E * 4);
    unsigned* staging = (unsigned*)alloc((size_t)E * 4);
    int*      pbh     = (int*)     alloc((size_t)NBLK * 512 * 4);
    int*      btot    = (int*)     alloc(512 * 4);
    int*      bbase   = (int*)     alloc(513 * 4);
    int*      flag    = (int*)     alloc(4);
    float*    stats   = (float*)   alloc(256 * 4);  // [0:128)=layer1, [128:256)=layer2
    unsigned short* bufA = (unsigned short*)alloc((size_t)N * D * 2);  // bf16 messages
    unsigned short* hbuf = (unsigned short*)alloc((size_t)N * D * 2);  // bf16 node feats
    float*    outf    = (float*)d_out;  // final fp32 output

    const int aggb = (N + 3) / 4;

    // ---- bucketed CSR build v4 (once, reused 3x; zero global atomics) ----
    detect_kernel<<<1, 256, 0, stream>>>((const unsigned int*)edges, flag);
    bucket_count_kernel<<<NBLK, 256, 0, stream>>>(edges, flag, pbh, E, shift);
    colscan_kernel<<<512, 256, 0, stream>>>(pbh, btot);
    basescan_kernel<<<1, 512, 0, stream>>>(btot, bbase, E);
    bucket_scatter_kernel<<<NBLK, 256, 0, stream>>>(edges, flag, pbh, bbase, staging, E, shift);
    bucket_fill_kernel<<<nbuk, 256, 0, stream>>>(staging, bbase, offs, dinv, srcs, shift, N, E);
    hipMemsetAsync(stats, 0, 256 * 4, stream);  // both layers' stats in one memset

    // ---- layer 1 (x fp32 in; hbuf bf16 out) ----
    mm_bn_kernel<<<512, 256, 0, stream>>>(x, nullptr, 0, W1, nullptr, nullptr, nullptr, 0,
                                          inv_n, dinv, bufA, N);
    agg_kernel<<<aggb, 256, 0, stream>>>(bufA, offs, srcs, dinv, b1, hbuf, nullptr, 1, N);
    bnstats_kernel<<<512, 256, 0, stream>>>(hbuf, stats, N);

    // ---- layer 2 (hbuf bf16 in; BN1+ReLU fused; hbuf bf16 out) ----
    mm_bn_kernel<<<512, 256, 0, stream>>>(nullptr, hbuf, 1, W2, stats, gamma1, beta1, 1,
                                          inv_n, dinv, bufA, N);
    agg_kernel<<<aggb, 256, 0, stream>>>(bufA, offs, srcs, dinv, b2, hbuf, nullptr, 1, N);
    bnstats_kernel<<<512, 256, 0, stream>>>(hbuf, stats + 128, N);

    // ---- layer 3 (hbuf bf16 in; BN2+ReLU fused; fp32 out to d_out) ----
    mm_bn_kernel<<<512, 256, 0, stream>>>(nullptr, hbuf, 1, W3, stats + 128, gamma2, beta2, 1,
                                          inv_n, dinv, bufA, N);
    agg_kernel<<<aggb, 256, 0, stream>>>(bufA, offs, srcs, dinv, b3, nullptr, outf, 0, N);
}